// Round 2
// 228.091 us; speedup vs baseline: 1.0656x; 1.0656x over previous
//
#include <hip/hip_runtime.h>

#define NUM_CLASS 20
#define IGNORE_V 255
#define WW 32
#define HH 256
#define DDEPTH 256
#define NVOX (DDEPTH * HH * WW)   // 2,097,152 voxels
#define CHUNK 1024                // voxels per block
#define NBLK (NVOX / CHUNK)       // 2048 blocks

// native vector type: __builtin_nontemporal_load rejects HIP_vector_type
typedef float f32x4 __attribute__((ext_vector_type(4)));

// sum_c |onehot_c(a) - onehot_c(b)|  (IGNORE -> all-zero onehot)
__device__ __forceinline__ float fpair(int a, int b) {
    return (a == b) ? 0.0f : ((a == IGNORE_V || b == IGNORE_V) ? 1.0f : 2.0f);
}

__global__ __launch_bounds__(256) void pal_main(
    const float* __restrict__ pred,
    const int*   __restrict__ tgt,
    const float* __restrict__ cw,
    float2*      __restrict__ partial)
{
    __shared__ float lcw[NUM_CLASS];
    if (threadIdx.x < NUM_CLASS) lcw[threadIdx.x] = cw[threadIdx.x];

    const int tid   = threadIdx.x;
    const int lane  = tid & 63;
    const int wid   = tid >> 6;
    const int base  = blockIdx.x * CHUNK;        // chunk base voxel
    const int v0    = base + tid * 4;            // this thread's 4-voxel run
    const int w0    = v0 & (WW - 1);
    const int h     = (v0 >> 5) & (HH - 1);
    const int d     = v0 >> 13;

    // ---- targets + neighbors (L2/L3-resident, cheap) ----
    const int4 t4 = *reinterpret_cast<const int4*>(tgt + v0);
    const int t[4] = {t4.x, t4.y, t4.z, t4.w};
    const int tm1 = tgt[v0 - ((w0 != 0) ? 1 : 0)];
    const int tp4 = tgt[v0 + 3 + ((w0 != WW - 4) ? 1 : 0)];
    const int4 tu4 = *reinterpret_cast<const int4*>(tgt + v0 - ((h != 0)          ? WW      : 0));
    const int4 td4 = *reinterpret_cast<const int4*>(tgt + v0 + ((h != HH - 1)     ? WW      : 0));
    const int4 tb4 = *reinterpret_cast<const int4*>(tgt + v0 - ((d != 0)          ? WW * HH : 0));
    const int4 tf4 = *reinterpret_cast<const int4*>(tgt + v0 + ((d != DDEPTH - 1) ? WW * HH : 0));

    // ---- direct streaming of all 20 classes ----
    // Each pred element is consumed exactly once by exactly one thread, so LDS
    // staging is pure overhead (2x vmcnt(0) barrier drains per phase + 40 KB
    // LDS capping residency at 4 blocks/CU). Lane i reads 16 contiguous bytes
    // at class-base + v0: per-class loads are perfectly coalesced 1 KB/wave,
    // one global_load_dwordx4 each off an SGPR base. Nontemporal: zero reuse,
    // don't evict the L2-resident tgt lines.
    const f32x4* gp = reinterpret_cast<const f32x4*>(pred + v0);
    float s[4]  = {0.f, 0.f, 0.f, 0.f};
    float pt[4] = {0.f, 0.f, 0.f, 0.f};
    #pragma unroll
    for (int c = 0; c < NUM_CLASS; c++) {
        const f32x4 x = __builtin_nontemporal_load(gp + (size_t)c * (NVOX / 4));
        #pragma unroll
        for (int j = 0; j < 4; j++) {
            s[j] += __expf(x[j]);
            if (t[j] == c) pt[j] = x[j];
        }
    }

    __syncthreads();   // lcw visible before use below (only barrier pre-reduction)

    // ---- LGA + loss ----
    const int tu[4] = {tu4.x, tu4.y, tu4.z, tu4.w};
    const int td[4] = {td4.x, td4.y, td4.z, td4.w};
    const int tb[4] = {tb4.x, tb4.y, tb4.z, tb4.w};
    const int tf[4] = {tf4.x, tf4.y, tf4.z, tf4.w};
    const float scH = (h == 0 || h == HH - 1)     ? 1.0f : 0.5f;
    const float scD = (d == 0 || d == DDEPTH - 1) ? 1.0f : 0.5f;

    float num = 0.0f, den = 0.0f;
    #pragma unroll
    for (int j = 0; j < 4; j++) {
        const int tj = t[j];
        if (tj != IGNORE_V) {
            const int wj = w0 + j;
            const int tL = (j > 0) ? t[j-1] : ((w0 == 0)      ? t[0] : tm1);
            const int tR = (j < 3) ? t[j+1] : ((w0 == WW - 4) ? t[3] : tp4);
            const float scW = (wj == 0 || wj == WW - 1) ? 1.0f : 0.5f;
            const float lga = scW * fpair(tL, tR)
                            + scH * fpair(tu[j], td[j])
                            + scD * fpair(tb[j], tf[j]);
            const float wt = lcw[tj];
            num += wt * (__logf(s[j]) - pt[j]) * (1.0f + lga);
            den += wt;
        }
    }

    // ---- wave + block reduction -> one partial per block, no atomics ----
    #pragma unroll
    for (int off = 32; off > 0; off >>= 1) {
        num += __shfl_down(num, off);
        den += __shfl_down(den, off);
    }
    __shared__ float sn[4], sd[4];
    if (lane == 0) { sn[wid] = num; sd[wid] = den; }
    __syncthreads();
    if (tid == 0)
        partial[blockIdx.x] = make_float2((sn[0] + sn[1]) + (sn[2] + sn[3]),
                                          (sd[0] + sd[1]) + (sd[2] + sd[3]));
}

// Single block reduces the 2048 partials (16 KB).
__global__ __launch_bounds__(256) void pal_final(
    const float2* __restrict__ partial, float* __restrict__ out)
{
    const float4* p4 = reinterpret_cast<const float4*>(partial);  // 1024 float4
    float num = 0.f, den = 0.f;
    #pragma unroll
    for (int k = 0; k < 4; k++) {
        const float4 f = p4[threadIdx.x + 256 * k];
        num += f.x + f.z;
        den += f.y + f.w;
    }
    #pragma unroll
    for (int off = 32; off > 0; off >>= 1) {
        num += __shfl_down(num, off);
        den += __shfl_down(den, off);
    }
    __shared__ float sn[4], sd[4];
    const int lane = threadIdx.x & 63;
    const int wid  = threadIdx.x >> 6;
    if (lane == 0) { sn[wid] = num; sd[wid] = den; }
    __syncthreads();
    if (threadIdx.x == 0)
        out[0] = ((sn[0] + sn[1]) + (sn[2] + sn[3])) /
                 ((sd[0] + sd[1]) + (sd[2] + sd[3]));
}

extern "C" void kernel_launch(void* const* d_in, const int* in_sizes, int n_in,
                              void* d_out, int out_size, void* d_ws, size_t ws_size,
                              hipStream_t stream) {
    const float* pred = (const float*)d_in[0];
    const int*   tgt  = (const int*)d_in[1];
    const float* cw   = (const float*)d_in[2];
    float*  out     = (float*)d_out;
    float2* partial = (float2*)d_ws;

    pal_main<<<NBLK, 256, 0, stream>>>(pred, tgt, cw, partial);
    pal_final<<<1, 256, 0, stream>>>(partial, out);
}